// Round 13
// baseline (91.775 us; speedup 1.0000x reference)
//
#include <hip/hip_runtime.h>
#include <hip/hip_bf16.h>
#include <math.h>

constexpr int BROWS = 4096;   // batch (M)
constexpr int DDIM  = 2048;   // input features (K)
constexpr int NCOMP = 4;
constexpr int DCOMP = 1024;
constexpr int NOUT  = NCOMP * DCOMP;  // 4096 output cols

typedef __attribute__((ext_vector_type(8))) short bf16x8;
typedef __attribute__((ext_vector_type(4))) float f32x4;
typedef __attribute__((ext_vector_type(4))) short s16x4;

__device__ __forceinline__ short f2bf(float f) {
  union { float f; unsigned u; } v; v.f = f;
  unsigned r = v.u + 0x7FFFu + ((v.u >> 16) & 1u);  // round-to-nearest-even
  return (short)(r >> 16);
}

#define GLOAD_LDS16(gptr, lptr) __builtin_amdgcn_global_load_lds( \
    (const __attribute__((address_space(1))) void*)(gptr),        \
    (__attribute__((address_space(3))) void*)(lptr), 16, 0, 0)

// =======================================================================
// Prep (r5-proven, ~19.5us, at HBM roofline: 96MB traffic / 6.3TB/s):
// blocks [0,1024) gating (1 row/wave) + x f32->bf16; [1024,3072) Wc
// transpose+convert to B^T bf16.
// =======================================================================
__global__ __launch_bounds__(256) void prep_kernel(
    const float* __restrict__ x, const float* __restrict__ noise,
    const float* __restrict__ Wg, const float* __restrict__ bg,
    const float* __restrict__ Wn, const float* __restrict__ bn,
    const float* __restrict__ Wc,
    float* __restrict__ Gout, short* __restrict__ xb, short* __restrict__ WcT) {
  __shared__ float tile[64][65];
  const int bid = blockIdx.x;
  const int tid = threadIdx.x;

  if (bid < 1024) {
    const int lane = tid & 63;
    const int row  = bid * 4 + (tid >> 6);
    const float* xr = x + (size_t)row * DDIM;
    short* xbr = xb + (size_t)row * DDIM;

    float ag[4] = {0.f, 0.f, 0.f, 0.f};
    float an[4] = {0.f, 0.f, 0.f, 0.f};
#pragma unroll
    for (int i = 0; i < 8; i++) {
      int d = i * 256 + lane * 4;
      float4 v = *reinterpret_cast<const float4*>(xr + d);
      s16x4 s; s.x = f2bf(v.x); s.y = f2bf(v.y); s.z = f2bf(v.z); s.w = f2bf(v.w);
      *reinterpret_cast<s16x4*>(xbr + d) = s;
      float xv[4] = {v.x, v.y, v.z, v.w};
#pragma unroll
      for (int j = 0; j < 4; j++) {
        float4 wg = *reinterpret_cast<const float4*>(Wg + 4 * (d + j));
        float4 wn = *reinterpret_cast<const float4*>(Wn + 4 * (d + j));
        ag[0] += xv[j] * wg.x; ag[1] += xv[j] * wg.y;
        ag[2] += xv[j] * wg.z; ag[3] += xv[j] * wg.w;
        an[0] += xv[j] * wn.x; an[1] += xv[j] * wn.y;
        an[2] += xv[j] * wn.z; an[3] += xv[j] * wn.w;
      }
    }
#pragma unroll
    for (int off = 32; off > 0; off >>= 1) {
#pragma unroll
      for (int c = 0; c < 4; c++) {
        ag[c] += __shfl_xor(ag[c], off);
        an[c] += __shfl_xor(an[c], off);
      }
    }
    if (lane == 0) {
      float H[4];
#pragma unroll
      for (int c = 0; c < 4; c++) {
        float v  = an[c] + bn[c];
        float sp = (v > 20.f) ? v : log1pf(expf(v));
        H[c] = (ag[c] + bg[c]) + noise[(size_t)row * NCOMP + c] * sp;
      }
      int k = 0; float best = H[0];
#pragma unroll
      for (int c = 1; c < 4; c++) { if (H[c] > best) { best = H[c]; k = c; } }
#pragma unroll
      for (int c = 0; c < 4; c++)
        Gout[(size_t)row * NCOMP + c] = (c <= k) ? 1.0f : 0.0f;
    }
  } else {
    const int tb  = bid - 1024;
    const int o_t = tb & 15, d_t = (tb >> 4) & 31, c = tb >> 9;
    const int d0 = d_t * 64, o0 = o_t * 64;
    const int col = tid & 63, rb = tid >> 6;

    const float* src = Wc + ((size_t)c * DDIM + d0) * DCOMP + o0;
#pragma unroll
    for (int i = 0; i < 16; i++) {
      int r = rb + i * 4;
      tile[r][col] = src[(size_t)r * DCOMP + col];
    }
    __syncthreads();
    short* dst = WcT + ((size_t)c * DCOMP + o0) * DDIM + d0;
    const int o   = tid >> 2;
    const int dsb = (tid & 3) * 16;
    bf16x8 p0, p1;
#pragma unroll
    for (int k = 0; k < 8; k++) {
      p0[k] = f2bf(tile[dsb + k][o]);
      p1[k] = f2bf(tile[dsb + 8 + k][o]);
    }
    *reinterpret_cast<bf16x8*>(dst + (size_t)o * DDIM + dsb)     = p0;
    *reinterpret_cast<bf16x8*>(dst + (size_t)o * DDIM + dsb + 8) = p1;
  }
}

// =======================================================================
// Main GEMM, round-13: r9 chassis with the two ZERO-READ phases (p4, p8)
// MERGED into p3/p7 -> 6 phases, 12 barriers/iter (was 16), 32-MFMA
// clusters at p3'/p7'. Mechanism targeted: with 1 block/CU, every barrier
// costs arrival-skew serially; removing 4 barriers + 2 lgkm stalls per
// iter attacks the measured ~4500 vs ~1500 cyc/K-tile gap.
// Ledger (audited r13): stages p1:B1.Ah1<-t1  p2:B0.Ah0<-t2
//   p3':B0.Bh0,B0.Bh1<-t2  p5:B0.Ah1<-t2  p6:B1.Ah0<-t3  p7':B1.Bh0,Bh1<-t3
// Reads: p1: a<-B0.Ah0, bA<-B0.Bh0 | p2: bB<-B0.Bh1 | p3': a<-B0.Ah1
//        p5: a<-B1.Ah0, bA<-B1.Bh0 | p6: bB<-B1.Bh1 | p7': a<-B1.Ah1
// MFMA:  p1(0,0)bA p2(0,2)bB p3'(4,2)bB+(4,0)bA  (same for buf1 p5-p7')
// vmcnt(6) only at p3'/p7' ends (3 half-tiles in flight). Tight pairs
// (read@p, staged@p+1) all retain the post-MFMA barrier. lgkm(8) hint
// pre-barrier on 12-read phases p1/p5 (template's optional line).
// =======================================================================
constexpr int BM = 256, BN = 256, BK = 64;
constexpr int NT = DDIM / BK;    // 32 K-tiles
constexpr int HS = 128 * 64;     // shorts per half-tile (16 KB)

#define BAR __builtin_amdgcn_s_barrier()

template<int MB, int NB>
__device__ __forceinline__ void MFc(f32x4 (&acc)[8][4], bf16x8 (&a)[4][2], bf16x8 (&b)[2][2]) {
#pragma unroll
  for (int kh = 0; kh < 2; kh++)
#pragma unroll
    for (int ml = 0; ml < 4; ml++)
#pragma unroll
      for (int nl = 0; nl < 2; nl++)
        acc[MB + ml][NB + nl] = __builtin_amdgcn_mfma_f32_16x16x32_bf16(
            a[ml][kh], b[nl][kh], acc[MB + ml][NB + nl], 0, 0, 0);
}

// 16-MFMA phase: barrier -> bare lgkm(0) -> prio cluster
#define PH16(MB, NB, BREG)                                   \
  BAR;                                                       \
  asm volatile("s_waitcnt lgkmcnt(0)");                      \
  __builtin_amdgcn_s_setprio(1);                             \
  MFc<MB, NB>(acc, a, BREG);                                 \
  __builtin_amdgcn_s_setprio(0);

// 32-MFMA merged phase (p3'/p7'): both mh1 quadrants back-to-back
#define PH32(BREG1, BREG0)                                   \
  BAR;                                                       \
  asm volatile("s_waitcnt lgkmcnt(0)");                      \
  __builtin_amdgcn_s_setprio(1);                             \
  MFc<4, 2>(acc, a, BREG1);                                  \
  MFc<4, 0>(acc, a, BREG0);                                  \
  __builtin_amdgcn_s_setprio(0);

__global__ __launch_bounds__(512, 2) void gemm_kernel(
    const short* __restrict__ xb, const short* __restrict__ wt,
    const float* __restrict__ bc, const float* __restrict__ G,
    float* __restrict__ E) {
  __shared__ short Asm[2][2][HS];   // [buf][row-half][128r * 8slot * 8bf16]
  __shared__ short Bsm[2][2][HS];   // [buf][col-half][...]

  const int tid  = threadIdx.x;
  const int wave = tid >> 6, lane = tid & 63;
  const int wm = wave >> 2, wn = wave & 3;
  const int fr = lane & 15, fq = lane >> 4, l7 = lane & 7;

  // XCD swizzle: 16x16 tile grid, 8 XCDs, each owns a 4x8 chunk (col-major)
  const int xcd = blockIdx.x & 7, j = blockIdx.x >> 3;
  const int trow0 = (((xcd >> 1) << 2) + (j & 3)) * BM;
  const int tcol0 = (((xcd & 1) << 3) + (j >> 2)) * BN;

  const short* baseA[2] = { xb + (size_t)(trow0      ) * DDIM,
                            xb + (size_t)(trow0 + 128) * DDIM };
  const short* baseB[2] = { wt + (size_t)(tcol0      ) * DDIM,
                            wt + (size_t)(tcol0 + 128) * DDIM };

  // per-lane staging offsets (linear LDS dest, inverse-swizzled source)
  size_t soff[2]; int ldst[2];
#pragma unroll
  for (int l = 0; l < 2; l++) {
    int f = l * 512 + tid;
    int r = f >> 3;
    int s = (f & 7) ^ (r & 7);
    soff[l] = (size_t)r * DDIM + s * 8;
    ldst[l] = (l * 512 + wave * 64) * 8;   // wave-uniform LDS base (shorts)
  }

  auto STAGE = [&](const short* gb, int t, short* ldsh) {
#pragma unroll
    for (int l = 0; l < 2; l++)
      GLOAD_LDS16(gb + t * 64 + soff[l], ldsh + ldst[l]);
  };
  auto LDA = [&](const short* Ah, bf16x8 (&a)[4][2]) {
#pragma unroll
    for (int ml = 0; ml < 4; ml++) {
      int rh = wm * 64 + ml * 16 + fr;
#pragma unroll
      for (int kh = 0; kh < 2; kh++) {
        int sl = ((kh * 4 + fq) ^ l7) * 8;
        a[ml][kh] = *reinterpret_cast<const bf16x8*>(Ah + rh * 64 + sl);
      }
    }
  };
  auto LDB = [&](const short* Bh, bf16x8 (&b)[2][2]) {
#pragma unroll
    for (int nl = 0; nl < 2; nl++) {
      int ch = wn * 32 + nl * 16 + fr;
#pragma unroll
      for (int kh = 0; kh < 2; kh++) {
        int sl = ((kh * 4 + fq) ^ l7) * 8;
        b[nl][kh] = *reinterpret_cast<const bf16x8*>(Bh + ch * 64 + sl);
      }
    }
  };

  f32x4 acc[8][4];
#pragma unroll
  for (int m = 0; m < 8; m++)
#pragma unroll
    for (int n = 0; n < 4; n++) acc[m][n] = f32x4{0.f, 0.f, 0.f, 0.f};
  bf16x8 a[4][2], bA[2][2], bB[2][2];

  // ---- prologue (r9 verbatim): tile0 (4 halves) + tile1 {Ah0,Bh0,Bh1};
  // vmcnt(6) keeps the tile1 trio in flight; tile1.Ah1 staged at p1. ----
  STAGE(baseA[0], 0, &Asm[0][0][0]);
  STAGE(baseB[0], 0, &Bsm[0][0][0]);
  STAGE(baseB[1], 0, &Bsm[0][1][0]);
  STAGE(baseA[1], 0, &Asm[0][1][0]);
  STAGE(baseA[0], 1, &Asm[1][0][0]);
  STAGE(baseB[0], 1, &Bsm[1][0][0]);
  STAGE(baseB[1], 1, &Bsm[1][1][0]);
  asm volatile("s_waitcnt vmcnt(6)" ::: "memory");
  BAR;

  // ---- main loop (iters 0..NT/2-2, branch-free, 6 phases) ----
  for (int i = 0; i < NT / 2 - 1; i++) {
    const int t1 = 2 * i + 1, t2 = 2 * i + 2, t3 = 2 * i + 3;

    // p1: reads a<-B0.Ah0, bA<-B0.Bh0 (12 reads, lgkm(8) hint); MFMA(0,0)
    LDA(&Asm[0][0][0], a); LDB(&Bsm[0][0][0], bA);
    STAGE(baseA[1], t1, &Asm[1][1][0]);
    asm volatile("s_waitcnt lgkmcnt(8)");
    PH16(0, 0, bA);
    BAR;   // tight pair p1->p2 (B0.Ah0)
    // p2: reads bB<-B0.Bh1; MFMA(0,2)
    LDB(&Bsm[0][1][0], bB);
    STAGE(baseA[0], t2, &Asm[0][0][0]);
    PH16(0, 2, bB);
    BAR;   // tight pair p2->p3' (B0.Bh1)
    // p3' (merged p3+p4): reads a<-B0.Ah1; 32 MFMA; vmcnt(6)
    LDA(&Asm[0][1][0], a);
    STAGE(baseB[0], t2, &Bsm[0][0][0]); STAGE(baseB[1], t2, &Bsm[0][1][0]);
    PH32(bB, bA);
    asm volatile("s_waitcnt vmcnt(6)" ::: "memory");
    BAR;   // publish + tight pair p3'->p5 (B0.Ah1)
    // p5: reads a<-B1.Ah0, bA<-B1.Bh0; MFMA(0,0)
    LDA(&Asm[1][0][0], a); LDB(&Bsm[1][0][0], bA);
    STAGE(baseA[1], t2, &Asm[0][1][0]);
    asm volatile("s_waitcnt lgkmcnt(8)");
    PH16(0, 0, bA);
    BAR;   // tight pair p5->p6 (B1.Ah0)
    // p6: reads bB<-B1.Bh1; MFMA(0,2)
    LDB(&Bsm[1][1][0], bB);
    STAGE(baseA[0], t3, &Asm[1][0][0]);
    PH16(0, 2, bB);
    BAR;   // tight pair p6->p7' (B1.Bh1)
    // p7' (merged p7+p8): reads a<-B1.Ah1; 32 MFMA; vmcnt(6)
    LDA(&Asm[1][1][0], a);
    STAGE(baseB[0], t3, &Bsm[1][0][0]); STAGE(baseB[1], t3, &Bsm[1][1][0]);
    PH32(bB, bA);
    asm volatile("s_waitcnt vmcnt(6)" ::: "memory");
    BAR;   // publish + tight pair p7'->p1next (B1.Ah1)
  }

  // ---- peel (tiles NT-2 buf0, NT-1 buf1): keeps only p1's stage
  // (buf1.Ah1 <- NT-1); p3''s vmcnt(0) drains everything. ----
  {
    // p1
    LDA(&Asm[0][0][0], a); LDB(&Bsm[0][0][0], bA);
    STAGE(baseA[1], NT - 1, &Asm[1][1][0]);
    asm volatile("s_waitcnt lgkmcnt(8)");
    PH16(0, 0, bA);
    BAR;
    // p2
    LDB(&Bsm[0][1][0], bB);
    PH16(0, 2, bB);
    BAR;
    // p3' + full drain
    LDA(&Asm[0][1][0], a);
    PH32(bB, bA);
    asm volatile("s_waitcnt vmcnt(0)" ::: "memory");
    BAR;
    // p5
    LDA(&Asm[1][0][0], a); LDB(&Bsm[1][0][0], bA);
    asm volatile("s_waitcnt lgkmcnt(8)");
    PH16(0, 0, bA);
    BAR;
    // p6
    LDB(&Bsm[1][1][0], bB);
    PH16(0, 2, bB);
    BAR;
    // p7'
    LDA(&Asm[1][1][0], a);
    PH32(bB, bA);
  }

  // ---- epilogue: + bias, * mask, store f32 (r9 form, unchanged) ----
  const int comp = tcol0 >> 10;
  const float* __restrict__ bcn = bc + (size_t)comp * DCOMP + (tcol0 & (DCOMP - 1));
  float bias[4];
#pragma unroll
  for (int n = 0; n < 4; n++)
    bias[n] = bcn[((n >> 1) * 128) + wn * 32 + (n & 1) * 16 + fr];
#pragma unroll
  for (int m = 0; m < 8; m++) {
    int growb = trow0 + ((m >> 2) * 128) + wm * 64 + (m & 3) * 16 + fq * 4;
#pragma unroll
    for (int j2 = 0; j2 < 4; j2++) {
      int r = growb + j2;
      float mval = G[(size_t)r * NCOMP + comp];
      float* Erow = E + (size_t)r * NOUT + tcol0;
#pragma unroll
      for (int n = 0; n < 4; n++) {
        int coll = ((n >> 1) * 128) + wn * 32 + (n & 1) * 16 + fr;
        Erow[coll] = mval * (acc[m][n][j2] + bias[n]);
      }
    }
  }
}

extern "C" void kernel_launch(void* const* d_in, const int* in_sizes, int n_in,
                              void* d_out, int out_size, void* d_ws, size_t ws_size,
                              hipStream_t stream) {
  const float* x     = (const float*)d_in[0];
  const float* noise = (const float*)d_in[1];
  const float* Wc    = (const float*)d_in[2];
  const float* bc    = (const float*)d_in[3];
  const float* Wg    = (const float*)d_in[4];
  const float* bg    = (const float*)d_in[5];
  const float* Wn    = (const float*)d_in[6];
  const float* bn    = (const float*)d_in[7];

  float* E = (float*)d_out;                          // [4096, 4096]
  float* G = (float*)d_out + (size_t)BROWS * NOUT;   // [4096, 4]

  short* xb  = (short*)d_ws;                         // 16 MB bf16
  short* WcT = xb + (size_t)BROWS * DDIM;            // 16 MB bf16

  prep_kernel<<<3072, 256, 0, stream>>>(x, noise, Wg, bg, Wn, bn, Wc, G, xb, WcT);
  gemm_kernel<<<256, 512, 0, stream>>>(xb, WcT, bc, G, E);
}

// Round 14
// 90.572 us; speedup vs baseline: 1.0133x; 1.0133x over previous
//
#include <hip/hip_runtime.h>
#include <hip/hip_bf16.h>
#include <math.h>

constexpr int BROWS = 4096;   // batch (M)
constexpr int DDIM  = 2048;   // input features (K)
constexpr int NCOMP = 4;
constexpr int DCOMP = 1024;
constexpr int NOUT  = NCOMP * DCOMP;  // 4096 output cols

typedef __attribute__((ext_vector_type(8))) short bf16x8;
typedef __attribute__((ext_vector_type(4))) float f32x4;
typedef __attribute__((ext_vector_type(4))) short s16x4;

__device__ __forceinline__ short f2bf(float f) {
  union { float f; unsigned u; } v; v.f = f;
  unsigned r = v.u + 0x7FFFu + ((v.u >> 16) & 1u);  // round-to-nearest-even
  return (short)(r >> 16);
}

#define GLOAD_LDS16(gptr, lptr) __builtin_amdgcn_global_load_lds( \
    (const __attribute__((address_space(1))) void*)(gptr),        \
    (__attribute__((address_space(3))) void*)(lptr), 16, 0, 0)

// =======================================================================
// Prep (r5-proven, ~19.5us, 78% of HBM roofline for its 96MB traffic):
// blocks [0,1024) gating (1 row/wave) + x f32->bf16; [1024,3072) Wc
// transpose+convert to B^T bf16.
// =======================================================================
__global__ __launch_bounds__(256) void prep_kernel(
    const float* __restrict__ x, const float* __restrict__ noise,
    const float* __restrict__ Wg, const float* __restrict__ bg,
    const float* __restrict__ Wn, const float* __restrict__ bn,
    const float* __restrict__ Wc,
    float* __restrict__ Gout, short* __restrict__ xb, short* __restrict__ WcT) {
  __shared__ float tile[64][65];
  const int bid = blockIdx.x;
  const int tid = threadIdx.x;

  if (bid < 1024) {
    const int lane = tid & 63;
    const int row  = bid * 4 + (tid >> 6);
    const float* xr = x + (size_t)row * DDIM;
    short* xbr = xb + (size_t)row * DDIM;

    float ag[4] = {0.f, 0.f, 0.f, 0.f};
    float an[4] = {0.f, 0.f, 0.f, 0.f};
#pragma unroll
    for (int i = 0; i < 8; i++) {
      int d = i * 256 + lane * 4;
      float4 v = *reinterpret_cast<const float4*>(xr + d);
      s16x4 s; s.x = f2bf(v.x); s.y = f2bf(v.y); s.z = f2bf(v.z); s.w = f2bf(v.w);
      *reinterpret_cast<s16x4*>(xbr + d) = s;
      float xv[4] = {v.x, v.y, v.z, v.w};
#pragma unroll
      for (int j = 0; j < 4; j++) {
        float4 wg = *reinterpret_cast<const float4*>(Wg + 4 * (d + j));
        float4 wn = *reinterpret_cast<const float4*>(Wn + 4 * (d + j));
        ag[0] += xv[j] * wg.x; ag[1] += xv[j] * wg.y;
        ag[2] += xv[j] * wg.z; ag[3] += xv[j] * wg.w;
        an[0] += xv[j] * wn.x; an[1] += xv[j] * wn.y;
        an[2] += xv[j] * wn.z; an[3] += xv[j] * wn.w;
      }
    }
#pragma unroll
    for (int off = 32; off > 0; off >>= 1) {
#pragma unroll
      for (int c = 0; c < 4; c++) {
        ag[c] += __shfl_xor(ag[c], off);
        an[c] += __shfl_xor(an[c], off);
      }
    }
    if (lane == 0) {
      float H[4];
#pragma unroll
      for (int c = 0; c < 4; c++) {
        float v  = an[c] + bn[c];
        float sp = (v > 20.f) ? v : log1pf(expf(v));
        H[c] = (ag[c] + bg[c]) + noise[(size_t)row * NCOMP + c] * sp;
      }
      int k = 0; float best = H[0];
#pragma unroll
      for (int c = 1; c < 4; c++) { if (H[c] > best) { best = H[c]; k = c; } }
#pragma unroll
      for (int c = 0; c < 4; c++)
        Gout[(size_t)row * NCOMP + c] = (c <= k) ? 1.0f : 0.0f;
    }
  } else {
    const int tb  = bid - 1024;
    const int o_t = tb & 15, d_t = (tb >> 4) & 31, c = tb >> 9;
    const int d0 = d_t * 64, o0 = o_t * 64;
    const int col = tid & 63, rb = tid >> 6;

    const float* src = Wc + ((size_t)c * DDIM + d0) * DCOMP + o0;
#pragma unroll
    for (int i = 0; i < 16; i++) {
      int r = rb + i * 4;
      tile[r][col] = src[(size_t)r * DCOMP + col];
    }
    __syncthreads();
    short* dst = WcT + ((size_t)c * DCOMP + o0) * DDIM + d0;
    const int o   = tid >> 2;
    const int dsb = (tid & 3) * 16;
    bf16x8 p0, p1;
#pragma unroll
    for (int k = 0; k < 8; k++) {
      p0[k] = f2bf(tile[dsb + k][o]);
      p1[k] = f2bf(tile[dsb + 8 + k][o]);
    }
    *reinterpret_cast<bf16x8*>(dst + (size_t)o * DDIM + dsb)     = p0;
    *reinterpret_cast<bf16x8*>(dst + (size_t)o * DDIM + dsb + 8) = p1;
  }
}

// =======================================================================
// Main GEMM, round-14: r9 chassis verbatim (proven 72.3us: 16x16x32 MFMA,
// stage ledger, vmcnt(6)@p4/p8, bare lgkm(0)/phase, 128KiB dbuf LDS, XOR
// swizzle, XCD 4x8 chunks) + STAGGERED EPILOGUE: each output quadrant is
// final after its last peel phase -> store it there, overlapping the
// 64MB f32 write burst with the remaining peel MFMA phases. Stores are
// fire-and-forget (nothing waits on them until kernel end) and cannot
// cross the "memory" vmcnt asms -> sync ledger untouched.
// =======================================================================
constexpr int BM = 256, BN = 256, BK = 64;
constexpr int NT = DDIM / BK;    // 32 K-tiles
constexpr int HS = 128 * 64;     // shorts per half-tile (16 KB)

template<int MB, int NB>
__device__ __forceinline__ void MF(f32x4 (&acc)[8][4], bf16x8 (&a)[4][2], bf16x8 (&b)[2][2]) {
#pragma unroll
  for (int kh = 0; kh < 2; kh++)
#pragma unroll
    for (int ml = 0; ml < 4; ml++)
#pragma unroll
      for (int nl = 0; nl < 2; nl++)
        acc[MB + ml][NB + nl] = __builtin_amdgcn_mfma_f32_16x16x32_bf16(
            a[ml][kh], b[nl][kh], acc[MB + ml][NB + nl], 0, 0, 0);
}

#define PH_SYNC_MFMA(MB, NB, BREG)                           \
  __builtin_amdgcn_s_barrier();                              \
  asm volatile("s_waitcnt lgkmcnt(0)");                      \
  __builtin_amdgcn_s_setprio(1);                             \
  MF<MB, NB>(acc, a, BREG);                                  \
  __builtin_amdgcn_s_setprio(0);

__global__ __launch_bounds__(512, 2) void gemm_kernel(
    const short* __restrict__ xb, const short* __restrict__ wt,
    const float* __restrict__ bc, const float* __restrict__ G,
    float* __restrict__ E) {
  __shared__ short Asm[2][2][HS];   // [buf][row-half][128r * 8slot * 8bf16]
  __shared__ short Bsm[2][2][HS];   // [buf][col-half][...]

  const int tid  = threadIdx.x;
  const int wave = tid >> 6, lane = tid & 63;
  const int wm = wave >> 2, wn = wave & 3;
  const int fr = lane & 15, fq = lane >> 4, l7 = lane & 7;

  // XCD swizzle: 16x16 tile grid, 8 XCDs, each owns a 4x8 chunk (col-major)
  const int xcd = blockIdx.x & 7, j = blockIdx.x >> 3;
  const int trow0 = (((xcd >> 1) << 2) + (j & 3)) * BM;
  const int tcol0 = (((xcd & 1) << 3) + (j >> 2)) * BN;

  const short* baseA[2] = { xb + (size_t)(trow0      ) * DDIM,
                            xb + (size_t)(trow0 + 128) * DDIM };
  const short* baseB[2] = { wt + (size_t)(tcol0      ) * DDIM,
                            wt + (size_t)(tcol0 + 128) * DDIM };

  // per-lane staging offsets (linear LDS dest, inverse-swizzled source)
  size_t soff[2]; int ldst[2];
#pragma unroll
  for (int l = 0; l < 2; l++) {
    int f = l * 512 + tid;
    int r = f >> 3;
    int s = (f & 7) ^ (r & 7);
    soff[l] = (size_t)r * DDIM + s * 8;
    ldst[l] = (l * 512 + wave * 64) * 8;   // wave-uniform LDS base (shorts)
  }

  auto STAGE = [&](const short* gb, int t, short* ldsh) {
#pragma unroll
    for (int l = 0; l < 2; l++)
      GLOAD_LDS16(gb + t * 64 + soff[l], ldsh + ldst[l]);
  };
  auto LDA = [&](const short* Ah, bf16x8 (&a)[4][2]) {
#pragma unroll
    for (int ml = 0; ml < 4; ml++) {
      int rh = wm * 64 + ml * 16 + fr;
#pragma unroll
      for (int kh = 0; kh < 2; kh++) {
        int sl = ((kh * 4 + fq) ^ l7) * 8;
        a[ml][kh] = *reinterpret_cast<const bf16x8*>(Ah + rh * 64 + sl);
      }
    }
  };
  auto LDB = [&](const short* Bh, bf16x8 (&b)[2][2]) {
#pragma unroll
    for (int nl = 0; nl < 2; nl++) {
      int ch = wn * 32 + nl * 16 + fr;
#pragma unroll
      for (int kh = 0; kh < 2; kh++) {
        int sl = ((kh * 4 + fq) ^ l7) * 8;
        b[nl][kh] = *reinterpret_cast<const bf16x8*>(Bh + ch * 64 + sl);
      }
    }
  };

  f32x4 acc[8][4];
#pragma unroll
  for (int m = 0; m < 8; m++)
#pragma unroll
    for (int n = 0; n < 4; n++) acc[m][n] = f32x4{0.f, 0.f, 0.f, 0.f};
  bf16x8 a[4][2], bA[2][2], bB[2][2];

  // epilogue constants (cheap; bias loaded just before the peel)
  const int comp = tcol0 >> 10;
  const float* __restrict__ bcn = bc + (size_t)comp * DCOMP + (tcol0 & (DCOMP - 1));
  float bias[4];

  // quadrant store: rows MB..MB+3 (m-frags), cols NB..NB+1 of acc
  auto STORE_Q = [&](int MB, int NB) {
#pragma unroll
    for (int mq = 0; mq < 4; mq++) {
      int m = MB + mq;
      int growb = trow0 + ((m >> 2) * 128) + wm * 64 + (m & 3) * 16 + fq * 4;
#pragma unroll
      for (int j2 = 0; j2 < 4; j2++) {
        int r = growb + j2;
        float mval = G[(size_t)r * NCOMP + comp];
        float* Erow = E + (size_t)r * NOUT + tcol0;
#pragma unroll
        for (int nq = 0; nq < 2; nq++) {
          int n = NB + nq;
          int coll = ((n >> 1) * 128) + wn * 32 + (n & 1) * 16 + fr;
          Erow[coll] = mval * (acc[m][n][j2] + bias[n]);
        }
      }
    }
  };

  // ---- prologue: tile0 (4 halves) + tile1 {Ah0,Bh0,Bh1}; vmcnt(6) keeps
  // the tile1 trio in flight; tile1.Ah1 staged at p1 of iter 0. ----
  STAGE(baseA[0], 0, &Asm[0][0][0]);
  STAGE(baseB[0], 0, &Bsm[0][0][0]);
  STAGE(baseB[1], 0, &Bsm[0][1][0]);
  STAGE(baseA[1], 0, &Asm[0][1][0]);
  STAGE(baseA[0], 1, &Asm[1][0][0]);
  STAGE(baseB[0], 1, &Bsm[1][0][0]);
  STAGE(baseB[1], 1, &Bsm[1][1][0]);
  asm volatile("s_waitcnt vmcnt(6)" ::: "memory");
  __builtin_amdgcn_s_barrier();

  // ---- main loop (iters 0..NT/2-2, branch-free; r9 ledger verbatim) ----
  for (int i = 0; i < NT / 2 - 1; i++) {
    const int t1 = 2 * i + 1, t2 = 2 * i + 2, t3 = 2 * i + 3;

    // p1: (mh0, nh0) of buf0; bA <- B0.Bh0 (held through p4)
    LDA(&Asm[0][0][0], a); LDB(&Bsm[0][0][0], bA);
    STAGE(baseA[1], t1, &Asm[1][1][0]);
    PH_SYNC_MFMA(0, 0, bA);
    __builtin_amdgcn_s_barrier();
    // p2: (mh0, nh1); bB <- B0.Bh1
    LDB(&Bsm[0][1][0], bB);
    STAGE(baseA[0], t2, &Asm[0][0][0]);
    PH_SYNC_MFMA(0, 2, bB);
    __builtin_amdgcn_s_barrier();
    // p3: (mh1, nh1)
    LDA(&Asm[0][1][0], a);
    STAGE(baseB[0], t2, &Bsm[0][0][0]);
    PH_SYNC_MFMA(4, 2, bB);
    __builtin_amdgcn_s_barrier();
    // p4: (mh1, nh0) — pure registers + counted vmcnt
    STAGE(baseB[1], t2, &Bsm[0][1][0]);
    PH_SYNC_MFMA(4, 0, bA);
    asm volatile("s_waitcnt vmcnt(6)" ::: "memory");
    __builtin_amdgcn_s_barrier();
    // p5: (mh0, nh0) of buf1
    LDA(&Asm[1][0][0], a); LDB(&Bsm[1][0][0], bA);
    STAGE(baseA[1], t2, &Asm[0][1][0]);
    PH_SYNC_MFMA(0, 0, bA);
    __builtin_amdgcn_s_barrier();
    // p6: (mh0, nh1)
    LDB(&Bsm[1][1][0], bB);
    STAGE(baseA[0], t3, &Asm[1][0][0]);
    PH_SYNC_MFMA(0, 2, bB);
    __builtin_amdgcn_s_barrier();
    // p7: (mh1, nh1)
    LDA(&Asm[1][1][0], a);
    STAGE(baseB[0], t3, &Bsm[1][0][0]);
    PH_SYNC_MFMA(4, 2, bB);
    __builtin_amdgcn_s_barrier();
    // p8: (mh1, nh0) — pure registers + counted vmcnt
    STAGE(baseB[1], t3, &Bsm[1][1][0]);
    PH_SYNC_MFMA(4, 0, bA);
    asm volatile("s_waitcnt vmcnt(6)" ::: "memory");
    __builtin_amdgcn_s_barrier();
  }

  // bias for epilogue (4 loads, L2-hot) — just before the peel
#pragma unroll
  for (int n = 0; n < 4; n++)
    bias[n] = bcn[((n >> 1) * 128) + wn * 32 + (n & 1) * 16 + fr];

  // ---- peeled last iteration (tiles NT-2 buf0, NT-1 buf1): keeps only
  // the p1 stage (buf1.Ah1 <- NT-1); p4's vmcnt(0) drains everything.
  // Quadrant stores interleaved after their FINAL update (p5..p8). ----
  {
    // p1
    LDA(&Asm[0][0][0], a); LDB(&Bsm[0][0][0], bA);
    STAGE(baseA[1], NT - 1, &Asm[1][1][0]);
    PH_SYNC_MFMA(0, 0, bA);
    __builtin_amdgcn_s_barrier();
    // p2
    LDB(&Bsm[0][1][0], bB);
    PH_SYNC_MFMA(0, 2, bB);
    __builtin_amdgcn_s_barrier();
    // p3
    LDA(&Asm[0][1][0], a);
    PH_SYNC_MFMA(4, 2, bB);
    __builtin_amdgcn_s_barrier();
    // p4 + full drain
    PH_SYNC_MFMA(4, 0, bA);
    asm volatile("s_waitcnt vmcnt(0)" ::: "memory");
    __builtin_amdgcn_s_barrier();
    // p5 — quadrant (0,0) final -> store it under p6-p8
    LDA(&Asm[1][0][0], a); LDB(&Bsm[1][0][0], bA);
    PH_SYNC_MFMA(0, 0, bA);
    STORE_Q(0, 0);
    __builtin_amdgcn_s_barrier();
    // p6 — quadrant (0,2) final
    LDB(&Bsm[1][1][0], bB);
    PH_SYNC_MFMA(0, 2, bB);
    STORE_Q(0, 2);
    __builtin_amdgcn_s_barrier();
    // p7 — quadrant (4,2) final
    LDA(&Asm[1][1][0], a);
    PH_SYNC_MFMA(4, 2, bB);
    STORE_Q(4, 2);
    __builtin_amdgcn_s_barrier();
    // p8 — quadrant (4,0) final
    PH_SYNC_MFMA(4, 0, bA);
    STORE_Q(4, 0);
  }
}

extern "C" void kernel_launch(void* const* d_in, const int* in_sizes, int n_in,
                              void* d_out, int out_size, void* d_ws, size_t ws_size,
                              hipStream_t stream) {
  const float* x     = (const float*)d_in[0];
  const float* noise = (const float*)d_in[1];
  const float* Wc    = (const float*)d_in[2];
  const float* bc    = (const float*)d_in[3];
  const float* Wg    = (const float*)d_in[4];
  const float* bg    = (const float*)d_in[5];
  const float* Wn    = (const float*)d_in[6];
  const float* bn    = (const float*)d_in[7];

  float* E = (float*)d_out;                          // [4096, 4096]
  float* G = (float*)d_out + (size_t)BROWS * NOUT;   // [4096, 4]

  short* xb  = (short*)d_ws;                         // 16 MB bf16
  short* WcT = xb + (size_t)BROWS * DDIM;            // 16 MB bf16

  prep_kernel<<<3072, 256, 0, stream>>>(x, noise, Wg, bg, Wn, bn, Wc, G, xb, WcT);
  gemm_kernel<<<256, 512, 0, stream>>>(xb, WcT, bc, G, E);
}